// Round 1
// baseline (940.494 us; speedup 1.0000x reference)
//
#include <hip/hip_runtime.h>
#include <cstdint>

// Problem constants (from reference file)
#define N_NODES 50000
#define N_EDGES 800000
#define C 64          // IN_C == OUT_C
// GATE_C = 128, K = 2, LAMBDA_MAX = 2.0 -> diag term is exactly 0.

// ---------------- workspace layout (floats) ----------------
// [deg/dinv | Px | Ph | Prh | lw | z | rh]
static constexpr size_t OFF_DEG = 0;                       // N (padded to 50176, /4 ok)
static constexpr size_t OFF_PX  = 50176;                   // N*64
static constexpr size_t OFF_PH  = OFF_PX + (size_t)N_NODES * C;   // 3,250,176
static constexpr size_t OFF_PRH = OFF_PH + (size_t)N_NODES * C;   // 6,450,176
static constexpr size_t ZERO_N  = OFF_PRH + (size_t)N_NODES * C;  // 9,650,176 floats zeroed
static constexpr size_t OFF_LW  = ZERO_N;                  // E
static constexpr size_t OFF_Z   = OFF_LW + N_EDGES;        // N*64
static constexpr size_t OFF_RH  = OFF_Z + (size_t)N_NODES * C;    // N*64

__global__ void zero_kernel(float* __restrict__ p, int n4) {
    int i = blockIdx.x * blockDim.x + threadIdx.x;
    if (i < n4) ((float4*)p)[i] = make_float4(0.f, 0.f, 0.f, 0.f);
}

__global__ void deg_kernel(const int* __restrict__ row, const float* __restrict__ w,
                           float* __restrict__ deg) {
    int e = blockIdx.x * blockDim.x + threadIdx.x;
    if (e < N_EDGES) atomicAdd(&deg[row[e]], w[e]);
}

__global__ void dinv_kernel(float* __restrict__ deg) {
    int i = blockIdx.x * blockDim.x + threadIdx.x;
    if (i < N_NODES) {
        float d = deg[i];
        deg[i] = (d > 0.f) ? rsqrtf(d) : 0.f;
    }
}

__global__ void lw_kernel(const int* __restrict__ row, const int* __restrict__ col,
                          const float* __restrict__ w, const float* __restrict__ dinv,
                          float* __restrict__ lw) {
    int e = blockIdx.x * blockDim.x + threadIdx.x;
    if (e < N_EDGES) {
        // 2/lambda_max = 1.0
        lw[e] = -w[e] * dinv[row[e]] * dinv[col[e]];
    }
}

// Scatter prop for two feature arrays at once: Px += lw*x[col], Ph += lw*h[col]
// thread = (edge, channel); 64 consecutive threads share one edge -> coalesced
// gathers (256B) and coalesced atomic bursts (4 lines per edge per array).
__global__ void prop2_kernel(const int* __restrict__ row, const int* __restrict__ col,
                             const float* __restrict__ lw,
                             const float* __restrict__ x, const float* __restrict__ h,
                             float* __restrict__ Px, float* __restrict__ Ph) {
    int gid = blockIdx.x * blockDim.x + threadIdx.x;   // < E*64 = 51.2M
    int e = gid >> 6;
    int c = gid & 63;
    if (e >= N_EDGES) return;
    int r  = row[e];
    int cl = col[e];
    float l = lw[e];
    atomicAdd(&Px[r * C + c], l * x[cl * C + c]);
    atomicAdd(&Ph[r * C + c], l * h[cl * C + c]);
}

__global__ void prop1_kernel(const int* __restrict__ row, const int* __restrict__ col,
                             const float* __restrict__ lw,
                             const float* __restrict__ s, float* __restrict__ Ps) {
    int gid = blockIdx.x * blockDim.x + threadIdx.x;
    int e = gid >> 6;
    int c = gid & 63;
    if (e >= N_EDGES) return;
    atomicAdd(&Ps[row[e] * C + c], lw[e] * s[col[e] * C + c]);
}

// z/r gate GEMV: per node, in = [x|h|Px|Ph] (256), out = 128 (z:0-63, r:64-127)
// z_pre[oc] = sum_k in[k] * W[k<128?0:1][k%128][oc] + b[oc]
__global__ __launch_bounds__(256) void gemm_zr_kernel(
        const float* __restrict__ x,  const float* __restrict__ h,
        const float* __restrict__ Px, const float* __restrict__ Ph,
        const float* __restrict__ Wz, const float* __restrict__ bz,
        const float* __restrict__ Wr, const float* __restrict__ br,
        float* __restrict__ z, float* __restrict__ rh) {
    __shared__ float in[2][256];
    int node0 = blockIdx.x * 2;
    int tid = threadIdx.x;
    for (int idx = tid; idx < 512; idx += 256) {
        int nl = idx >> 8, k = idx & 255;
        int node = node0 + nl;
        float v = 0.f;
        if (node < N_NODES) {
            if      (k < 64)  v = x [node * C + k];
            else if (k < 128) v = h [node * C + (k - 64)];
            else if (k < 192) v = Px[node * C + (k - 128)];
            else              v = Ph[node * C + (k - 192)];
        }
        in[nl][k] = v;
    }
    __syncthreads();
    int nl = tid >> 7, oc = tid & 127;
    int node = node0 + nl;
    if (node >= N_NODES) return;
    bool is_z = (oc < 64);
    int oce = oc & 63;
    const float* W = is_z ? Wz : Wr;
    float acc = is_z ? bz[oce] : br[oce];
    const float* W0 = W + oce;                 // W[0][k][oce] at stride 64
    const float* W1 = W + 128 * 64 + oce;      // W[1][k][oce]
    const float* v = in[nl];
    #pragma unroll 8
    for (int k = 0; k < 128; ++k) acc += v[k]       * W0[k * 64];
    #pragma unroll 8
    for (int k = 0; k < 128; ++k) acc += v[128 + k] * W1[k * 64];
    float sg = 1.f / (1.f + __expf(-acc));
    if (is_z) z [node * C + oce] = sg;
    else      rh[node * C + oce] = sg * h[node * C + oce];
}

// candidate GEMV + GRU blend: in = [x|rh|Px|Prh] (256), out 64
__global__ __launch_bounds__(256) void gemm_h_kernel(
        const float* __restrict__ x,  const float* __restrict__ rh,
        const float* __restrict__ Px, const float* __restrict__ Prh,
        const float* __restrict__ Wh, const float* __restrict__ bh,
        const float* __restrict__ z,  const float* __restrict__ h,
        float* __restrict__ out) {
    __shared__ float in[4][256];
    int node0 = blockIdx.x * 4;
    int tid = threadIdx.x;
    for (int idx = tid; idx < 1024; idx += 256) {
        int nl = idx >> 8, k = idx & 255;
        int node = node0 + nl;
        float v = 0.f;
        if (node < N_NODES) {
            if      (k < 64)  v = x  [node * C + k];
            else if (k < 128) v = rh [node * C + (k - 64)];
            else if (k < 192) v = Px [node * C + (k - 128)];
            else              v = Prh[node * C + (k - 192)];
        }
        in[nl][k] = v;
    }
    __syncthreads();
    int nl = tid >> 6, oc = tid & 63;
    int node = node0 + nl;
    if (node >= N_NODES) return;
    float acc = bh[oc];
    const float* W0 = Wh + oc;
    const float* W1 = Wh + 128 * 64 + oc;
    const float* v = in[nl];
    #pragma unroll 8
    for (int k = 0; k < 128; ++k) acc += v[k]       * W0[k * 64];
    #pragma unroll 8
    for (int k = 0; k < 128; ++k) acc += v[128 + k] * W1[k * 64];
    float ht = tanhf(acc);
    float zz = z[node * C + oc];
    out[node * C + oc] = (1.f - zz) * h[node * C + oc] + zz * ht;
}

extern "C" void kernel_launch(void* const* d_in, const int* in_sizes, int n_in,
                              void* d_out, int out_size, void* d_ws, size_t ws_size,
                              hipStream_t stream) {
    const float* x    = (const float*)d_in[0];
    const int*   eidx = (const int*)  d_in[1];   // [2, E]: row then col
    const float* w    = (const float*)d_in[2];
    const float* h    = (const float*)d_in[3];
    const float* Wz   = (const float*)d_in[4];
    const float* bz   = (const float*)d_in[5];
    const float* Wr   = (const float*)d_in[6];
    const float* br   = (const float*)d_in[7];
    const float* Wh   = (const float*)d_in[8];
    const float* bh   = (const float*)d_in[9];
    float* out = (float*)d_out;
    float* ws  = (float*)d_ws;

    const int* row = eidx;
    const int* col = eidx + N_EDGES;

    float* deg = ws + OFF_DEG;   // becomes dinv in-place
    float* Px  = ws + OFF_PX;
    float* Ph  = ws + OFF_PH;
    float* Prh = ws + OFF_PRH;
    float* lw  = ws + OFF_LW;
    float* z   = ws + OFF_Z;
    float* rh  = ws + OFF_RH;

    // 1. zero accumulators (deg + Px + Ph + Prh), ws is poisoned each call
    {
        int n4 = (int)(ZERO_N / 4);
        zero_kernel<<<(n4 + 255) / 256, 256, 0, stream>>>(ws, n4);
    }
    // 2. degree
    deg_kernel<<<(N_EDGES + 255) / 256, 256, 0, stream>>>(row, w, deg);
    // 3. dinv (in place)
    dinv_kernel<<<(N_NODES + 255) / 256, 256, 0, stream>>>(deg);
    // 4. normalized edge weights
    lw_kernel<<<(N_EDGES + 255) / 256, 256, 0, stream>>>(row, col, w, deg, lw);
    // 5. Px = Lhat@x, Ph = Lhat@h
    {
        int nthreads = N_EDGES * 64;
        prop2_kernel<<<(nthreads + 255) / 256, 256, 0, stream>>>(row, col, lw, x, h, Px, Ph);
    }
    // 6. z, r, rh = r*h
    gemm_zr_kernel<<<(N_NODES + 1) / 2, 256, 0, stream>>>(x, h, Px, Ph, Wz, bz, Wr, br, z, rh);
    // 7. Prh = Lhat@(r*h)
    {
        int nthreads = N_EDGES * 64;
        prop1_kernel<<<(nthreads + 255) / 256, 256, 0, stream>>>(row, col, lw, rh, Prh);
    }
    // 8. candidate + GRU blend -> out
    gemm_h_kernel<<<(N_NODES + 3) / 4, 256, 0, stream>>>(x, rh, Px, Prh, Wh, bh, z, h, out);
}

// Round 2
// 663.679 us; speedup vs baseline: 1.4171x; 1.4171x over previous
//
#include <hip/hip_runtime.h>
#include <cstdint>

#define N_NODES 50000
#define N_EDGES 800000
#define C 64
#define N_PAD 50176                 // 196 * 256
#define SCAN_BLOCKS 196

// ---------------- workspace layout (float units) ----------------
static constexpr size_t OFF_CNT  = 0;                 // N_PAD ints: count -> cursor
static constexpr size_t OFF_PART = 50176;             // 256 ints: block sums
static constexpr size_t OFF_POFF = 50432;             // 256 ints: scanned block offsets
static constexpr size_t OFF_DINV = 50688;             // N floats
static constexpr size_t OFF_CSR  = 100688;            // E int2 (8B-aligned: 100688*4 % 8 == 0)
static constexpr size_t OFF_LWC  = OFF_CSR + 2 * (size_t)N_EDGES;   // E floats (lw in CSR order)
static constexpr size_t OFF_PX   = OFF_LWC + N_EDGES;               // N*C
static constexpr size_t OFF_PH   = OFF_PX + (size_t)N_NODES * C;    // N*C (re-used for Prh)
static constexpr size_t OFF_RH   = OFF_PH + (size_t)N_NODES * C;    // N*C
// total ~12.1M floats = 48.4 MB

__global__ void zero_cnt_kernel(int* __restrict__ p) {
    int i = blockIdx.x * blockDim.x + threadIdx.x;    // N_PAD/4 = 12544 threads
    if (i < N_PAD / 4) ((int4*)p)[i] = make_int4(0, 0, 0, 0);
}

__global__ void hist_kernel(const int* __restrict__ row, int* __restrict__ cnt) {
    int e = blockIdx.x * blockDim.x + threadIdx.x;
    if (e < N_EDGES) atomicAdd(&cnt[row[e]], 1);
}

// per-block sums of cnt
__global__ __launch_bounds__(256) void scan_part_kernel(const int* __restrict__ cnt,
                                                        int* __restrict__ part) {
    __shared__ int s[256];
    int t = threadIdx.x;
    s[t] = cnt[blockIdx.x * 256 + t];
    __syncthreads();
    for (int d = 128; d > 0; d >>= 1) {
        if (t < d) s[t] += s[t + d];
        __syncthreads();
    }
    if (t == 0) part[blockIdx.x] = s[0];
}

// exclusive scan of 196 block sums (single block)
__global__ __launch_bounds__(256) void scan_root_kernel(const int* __restrict__ part,
                                                        int* __restrict__ poff) {
    __shared__ int s[256];
    int t = threadIdx.x;
    int v = (t < SCAN_BLOCKS) ? part[t] : 0;
    s[t] = v;
    __syncthreads();
    for (int d = 1; d < 256; d <<= 1) {
        int add = (t >= d) ? s[t - d] : 0;
        __syncthreads();
        s[t] += add;
        __syncthreads();
    }
    if (t < SCAN_BLOCKS) poff[t] = s[t] - v;   // exclusive
}

// per-block exclusive scan + offset -> cursor (= exclusive row prefix)
__global__ __launch_bounds__(256) void scan_add_kernel(const int* __restrict__ cnt,
                                                       const int* __restrict__ poff,
                                                       int* __restrict__ cursor) {
    __shared__ int s[256];
    int t = threadIdx.x;
    int i = blockIdx.x * 256 + t;
    int v = cnt[i];
    s[t] = v;
    __syncthreads();
    for (int d = 1; d < 256; d <<= 1) {
        int add = (t >= d) ? s[t - d] : 0;
        __syncthreads();
        s[t] += add;
        __syncthreads();
    }
    cursor[i] = s[t] - v + poff[blockIdx.x];
}

// scatter edges into CSR slots; cursor mutates so that afterwards
// cursor[n] == rowptr[n+1]  (start of node n = n? cursor[n-1] : 0)
__global__ void scatter_kernel(const int* __restrict__ row, const int* __restrict__ col,
                               const float* __restrict__ w,
                               int* __restrict__ cursor, int2* __restrict__ csr) {
    int e = blockIdx.x * blockDim.x + threadIdx.x;
    if (e >= N_EDGES) return;
    int pos = atomicAdd(&cursor[row[e]], 1);
    csr[pos] = make_int2(col[e], __float_as_int(w[e]));
}

// deg = sum of w over each node's CSR range; dinv = rsqrt(deg)
__global__ void degdinv_kernel(const int* __restrict__ cursor, const int2* __restrict__ csr,
                               float* __restrict__ dinv) {
    int n = blockIdx.x * blockDim.x + threadIdx.x;
    if (n >= N_NODES) return;
    int start = (n == 0) ? 0 : cursor[n - 1];
    int end = cursor[n];
    float d = 0.f;
    for (int e = start; e < end; ++e) d += __int_as_float(csr[e].y);
    dinv[n] = (d > 0.f) ? rsqrtf(d) : 0.f;
}

// Pull-prop: one wave per node, lane = channel. Computes lw on the fly
// (wave-uniform scalar loads), stores it for prop1, accumulates Px/Ph in regs.
__global__ __launch_bounds__(256) void prop2_gather_kernel(
        const int* __restrict__ cursor, const int2* __restrict__ csr,
        const float* __restrict__ dinv,
        const float* __restrict__ x, const float* __restrict__ h,
        float* __restrict__ lwc, float* __restrict__ Px, float* __restrict__ Ph) {
    int n = (blockIdx.x * 256 + threadIdx.x) >> 6;
    int lane = threadIdx.x & 63;
    if (n >= N_NODES) return;
    int start = (n == 0) ? 0 : cursor[n - 1];
    int end = cursor[n];
    float dn = dinv[n];
    float ax = 0.f, ah = 0.f;
    for (int e = start; e < end; ++e) {
        int2 cw = csr[e];
        int cl = cw.x;
        float l = -__int_as_float(cw.y) * dn * dinv[cl];
        if (lane == 0) lwc[e] = l;
        ax = fmaf(l, x[cl * C + lane], ax);
        ah = fmaf(l, h[cl * C + lane], ah);
    }
    Px[n * C + lane] = ax;
    Ph[n * C + lane] = ah;
}

__global__ __launch_bounds__(256) void prop1_gather_kernel(
        const int* __restrict__ cursor, const int2* __restrict__ csr,
        const float* __restrict__ lwc,
        const float* __restrict__ s, float* __restrict__ Ps) {
    int n = (blockIdx.x * 256 + threadIdx.x) >> 6;
    int lane = threadIdx.x & 63;
    if (n >= N_NODES) return;
    int start = (n == 0) ? 0 : cursor[n - 1];
    int end = cursor[n];
    float acc = 0.f;
    for (int e = start; e < end; ++e) {
        int cl = csr[e].x;
        acc = fmaf(lwc[e], s[cl * C + lane], acc);
    }
    Ps[n * C + lane] = acc;
}

// z/r gate GEMV: per node, in = [x|h|Px|Ph] (256), out = 128 (z:0-63, r:64-127)
__global__ __launch_bounds__(256) void gemm_zr_kernel(
        const float* __restrict__ x,  const float* __restrict__ h,
        const float* __restrict__ Px, const float* __restrict__ Ph,
        const float* __restrict__ Wz, const float* __restrict__ bz,
        const float* __restrict__ Wr, const float* __restrict__ br,
        float* __restrict__ z, float* __restrict__ rh) {
    __shared__ float in[2][256];
    int node0 = blockIdx.x * 2;
    int tid = threadIdx.x;
    for (int idx = tid; idx < 512; idx += 256) {
        int nl = idx >> 8, k = idx & 255;
        int node = node0 + nl;
        float v = 0.f;
        if (node < N_NODES) {
            if      (k < 64)  v = x [node * C + k];
            else if (k < 128) v = h [node * C + (k - 64)];
            else if (k < 192) v = Px[node * C + (k - 128)];
            else              v = Ph[node * C + (k - 192)];
        }
        in[nl][k] = v;
    }
    __syncthreads();
    int nl = tid >> 7, oc = tid & 127;
    int node = node0 + nl;
    if (node >= N_NODES) return;
    bool is_z = (oc < 64);
    int oce = oc & 63;
    const float* W = is_z ? Wz : Wr;
    float acc = is_z ? bz[oce] : br[oce];
    const float* W0 = W + oce;
    const float* W1 = W + 128 * 64 + oce;
    const float* v = in[nl];
    #pragma unroll 8
    for (int k = 0; k < 128; ++k) acc += v[k]       * W0[k * 64];
    #pragma unroll 8
    for (int k = 0; k < 128; ++k) acc += v[128 + k] * W1[k * 64];
    float sg = 1.f / (1.f + __expf(-acc));
    if (is_z) z [node * C + oce] = sg;
    else      rh[node * C + oce] = sg * h[node * C + oce];
}

// candidate GEMV + GRU blend: in = [x|rh|Px|Prh] (256), out 64
__global__ __launch_bounds__(256) void gemm_h_kernel(
        const float* __restrict__ x,  const float* __restrict__ rh,
        const float* __restrict__ Px, const float* __restrict__ Prh,
        const float* __restrict__ Wh, const float* __restrict__ bh,
        const float* __restrict__ z,  const float* __restrict__ h,
        float* __restrict__ out) {
    __shared__ float in[4][256];
    int node0 = blockIdx.x * 4;
    int tid = threadIdx.x;
    for (int idx = tid; idx < 1024; idx += 256) {
        int nl = idx >> 8, k = idx & 255;
        int node = node0 + nl;
        float v = 0.f;
        if (node < N_NODES) {
            if      (k < 64)  v = x  [node * C + k];
            else if (k < 128) v = rh [node * C + (k - 64)];
            else if (k < 192) v = Px [node * C + (k - 128)];
            else              v = Prh[node * C + (k - 192)];
        }
        in[nl][k] = v;
    }
    __syncthreads();
    int nl = tid >> 6, oc = tid & 63;
    int node = node0 + nl;
    if (node >= N_NODES) return;
    float acc = bh[oc];
    const float* W0 = Wh + oc;
    const float* W1 = Wh + 128 * 64 + oc;
    const float* v = in[nl];
    #pragma unroll 8
    for (int k = 0; k < 128; ++k) acc += v[k]       * W0[k * 64];
    #pragma unroll 8
    for (int k = 0; k < 128; ++k) acc += v[128 + k] * W1[k * 64];
    float ht = tanhf(acc);
    float zz = z[node * C + oc];
    out[node * C + oc] = (1.f - zz) * h[node * C + oc] + zz * ht;
}

extern "C" void kernel_launch(void* const* d_in, const int* in_sizes, int n_in,
                              void* d_out, int out_size, void* d_ws, size_t ws_size,
                              hipStream_t stream) {
    const float* x    = (const float*)d_in[0];
    const int*   eidx = (const int*)  d_in[1];   // [2, E]: row then col (int32 staged)
    const float* w    = (const float*)d_in[2];
    const float* h    = (const float*)d_in[3];
    const float* Wz   = (const float*)d_in[4];
    const float* bz   = (const float*)d_in[5];
    const float* Wr   = (const float*)d_in[6];
    const float* br   = (const float*)d_in[7];
    const float* Wh   = (const float*)d_in[8];
    const float* bh   = (const float*)d_in[9];
    float* out = (float*)d_out;
    float* ws  = (float*)d_ws;

    const int* row = eidx;
    const int* col = eidx + N_EDGES;

    int*   cnt    = (int*)(ws + OFF_CNT);     // becomes cursor
    int*   part   = (int*)(ws + OFF_PART);
    int*   poff   = (int*)(ws + OFF_POFF);
    float* dinv   = ws + OFF_DINV;
    int2*  csr    = (int2*)(ws + OFF_CSR);
    float* lwc    = ws + OFF_LWC;
    float* Px     = ws + OFF_PX;
    float* Ph     = ws + OFF_PH;    // re-used as Prh after gemm_zr consumes Ph
    float* rh     = ws + OFF_RH;
    float* z      = out;            // z lives in d_out until gemm_h overwrites it

    // ---- CSR build ----
    zero_cnt_kernel<<<(N_PAD / 4 + 255) / 256, 256, 0, stream>>>(cnt);
    hist_kernel<<<(N_EDGES + 255) / 256, 256, 0, stream>>>(row, cnt);
    scan_part_kernel<<<SCAN_BLOCKS, 256, 0, stream>>>(cnt, part);
    scan_root_kernel<<<1, 256, 0, stream>>>(part, poff);
    scan_add_kernel<<<SCAN_BLOCKS, 256, 0, stream>>>(cnt, poff, cnt /*cursor in-place*/);
    scatter_kernel<<<(N_EDGES + 255) / 256, 256, 0, stream>>>(row, col, w, cnt, csr);
    degdinv_kernel<<<(N_NODES + 255) / 256, 256, 0, stream>>>(cnt, csr, dinv);

    // ---- Px = Lhat@x, Ph = Lhat@h (pull, no atomics) ----
    prop2_gather_kernel<<<(N_NODES * 64 + 255) / 256, 256, 0, stream>>>(
        cnt, csr, dinv, x, h, lwc, Px, Ph);

    // ---- z, r, rh ----
    gemm_zr_kernel<<<(N_NODES + 1) / 2, 256, 0, stream>>>(x, h, Px, Ph, Wz, bz, Wr, br, z, rh);

    // ---- Prh = Lhat@(r*h)  (overwrites Ph slot) ----
    prop1_gather_kernel<<<(N_NODES * 64 + 255) / 256, 256, 0, stream>>>(cnt, csr, lwc, rh, Ph);

    // ---- candidate + GRU blend ----
    gemm_h_kernel<<<(N_NODES + 3) / 4, 256, 0, stream>>>(x, rh, Px, Ph, Wh, bh, z, h, out);
}

// Round 4
// 325.127 us; speedup vs baseline: 2.8927x; 2.0413x over previous
//
#include <hip/hip_runtime.h>
#include <cstdint>

#define N_NODES 50000
#define N_EDGES 800000
#define C 64
#define N_PAD 50176                 // 196 * 256
#define SCAN_BLOCKS 196

typedef __attribute__((ext_vector_type(8))) short bf16x8;   // 8 bf16 in 4 VGPRs
typedef __attribute__((ext_vector_type(4))) float f32x4;

// ---------------- workspace layout (float units) ----------------
// NOTE: Bzr = 32768 shorts = 16384 floats; Bh = 16384 shorts = 8192 floats.
// (Round-3 bug: these were halved, overlapping Bh with Bzr and Px with Bh ->
//  float data reinterpreted as bf16 -> NaN.)
static constexpr size_t OFF_CNT  = 0;                        // N_PAD ints (count -> cursor)
static constexpr size_t OFF_PART = 50176;                    // 256 ints
static constexpr size_t OFF_POFF = 50432;                    // 256 ints
static constexpr size_t OFF_DINV = 50688;                    // N floats
static constexpr size_t OFF_CSR  = 100864;                   // E int2
static constexpr size_t OFF_BZR  = OFF_CSR + 2 * (size_t)N_EDGES;   // 1,700,864: 16384 fl
static constexpr size_t OFF_BH   = OFF_BZR + 16384;                 // 8192 fl
static constexpr size_t OFF_PX   = OFF_BH + 8192;                   // N*C
static constexpr size_t OFF_PH   = OFF_PX + (size_t)N_NODES * C;    // N*C (later Prh)
static constexpr size_t OFF_XD   = OFF_PH + (size_t)N_NODES * C;    // N*C (later rhd)
static constexpr size_t OFF_HD   = OFF_XD + (size_t)N_NODES * C;    // N*C (later rh)
// total = OFF_HD + N*C = 14,525,440 floats = 58.1 MB (round-0 proved >= 67.4 MB)

__device__ __forceinline__ short f2bf(float f) {             // RNE fp32 -> bf16
    unsigned u = __float_as_uint(f);
    u += 0x7fffu + ((u >> 16) & 1u);
    return (short)(u >> 16);
}
__device__ __forceinline__ float fast_sigmoid(float v) {
    return 1.f / (1.f + __expf(-v));
}
__device__ __forceinline__ float fast_tanh(float v) {
    return 1.f - 2.f / (__expf(2.f * v) + 1.f);
}

// ======================= CSR build =======================
__global__ void zero_cnt_kernel(int* __restrict__ p) {
    int i = blockIdx.x * blockDim.x + threadIdx.x;
    if (i < N_PAD / 4) ((int4*)p)[i] = make_int4(0, 0, 0, 0);
}

__global__ void hist_kernel(const int* __restrict__ row, int* __restrict__ cnt) {
    int e = blockIdx.x * blockDim.x + threadIdx.x;
    if (e < N_EDGES) atomicAdd(&cnt[row[e]], 1);
}

__global__ __launch_bounds__(256) void scan_part_kernel(const int* __restrict__ cnt,
                                                        int* __restrict__ part) {
    __shared__ int s[256];
    int t = threadIdx.x;
    s[t] = cnt[blockIdx.x * 256 + t];
    __syncthreads();
    for (int d = 128; d > 0; d >>= 1) {
        if (t < d) s[t] += s[t + d];
        __syncthreads();
    }
    if (t == 0) part[blockIdx.x] = s[0];
}

__global__ __launch_bounds__(256) void scan_root_kernel(const int* __restrict__ part,
                                                        int* __restrict__ poff) {
    __shared__ int s[256];
    int t = threadIdx.x;
    int v = (t < SCAN_BLOCKS) ? part[t] : 0;
    s[t] = v;
    __syncthreads();
    for (int d = 1; d < 256; d <<= 1) {
        int add = (t >= d) ? s[t - d] : 0;
        __syncthreads();
        s[t] += add;
        __syncthreads();
    }
    if (t < SCAN_BLOCKS) poff[t] = s[t] - v;
}

__global__ __launch_bounds__(256) void scan_add_kernel(const int* __restrict__ cnt,
                                                       const int* __restrict__ poff,
                                                       int* __restrict__ cursor) {
    __shared__ int s[256];
    int t = threadIdx.x;
    int i = blockIdx.x * 256 + t;
    int v = cnt[i];
    s[t] = v;
    __syncthreads();
    for (int d = 1; d < 256; d <<= 1) {
        int add = (t >= d) ? s[t - d] : 0;
        __syncthreads();
        s[t] += add;
        __syncthreads();
    }
    cursor[i] = s[t] - v + poff[blockIdx.x];
}

// after this, cursor[n] == rowptr[n+1]
__global__ void scatter_kernel(const int* __restrict__ row, const int* __restrict__ col,
                               const float* __restrict__ w,
                               int* __restrict__ cursor, int2* __restrict__ csr) {
    int e = blockIdx.x * blockDim.x + threadIdx.x;
    if (e >= N_EDGES) return;
    int pos = atomicAdd(&cursor[row[e]], 1);
    csr[pos] = make_int2(col[e], __float_as_int(w[e]));
}

__global__ void degdinv_kernel(const int* __restrict__ cursor, const int2* __restrict__ csr,
                               float* __restrict__ dinv) {
    int n = blockIdx.x * blockDim.x + threadIdx.x;
    if (n >= N_NODES) return;
    int start = (n == 0) ? 0 : cursor[n - 1];
    int end = cursor[n];
    float d = 0.f;
    for (int e = start; e < end; ++e) d += __int_as_float(csr[e].y);
    dinv[n] = (d > 0.f) ? rsqrtf(d) : 0.f;
}

// xd = x*dinv, hd = h*dinv  (float4-vectorized)
__global__ void xdhd_kernel(const float* __restrict__ x, const float* __restrict__ h,
                            const float* __restrict__ dinv,
                            float* __restrict__ xd, float* __restrict__ hd) {
    int i = blockIdx.x * blockDim.x + threadIdx.x;   // N*16 float4 groups
    if (i >= N_NODES * 16) return;
    float d = dinv[i >> 4];
    float4 xv = ((const float4*)x)[i];
    float4 hv = ((const float4*)h)[i];
    ((float4*)xd)[i] = make_float4(xv.x * d, xv.y * d, xv.z * d, xv.w * d);
    ((float4*)hd)[i] = make_float4(hv.x * d, hv.y * d, hv.z * d, hv.w * d);
}

// Pack weights into bf16 B-fragment order for mfma_f32_16x16x32_bf16.
// Bpack[(kt*NCT+ct)*512 + lane*8 + j] = B[kt*32 + (lane>>4)*8 + j][ct*16 + (lane&15)]
// Bzr cols: 0-63 = Wz, 64-127 = Wr.  Row k: k<128 -> W[0][k], else W[1][k-128].
__global__ void pack_kernel(const float* __restrict__ Wz, const float* __restrict__ Wr,
                            const float* __restrict__ Wh,
                            short* __restrict__ Bzr, short* __restrict__ Bh) {
    int gid = blockIdx.x * blockDim.x + threadIdx.x;   // 6144 threads
    if (gid < 4096) {                                   // zr: 64 (kt,ct) x 64 lanes
        int ktct = gid >> 6, lane = gid & 63;
        int kt = ktct >> 3, ct = ktct & 7;
        int colg = ct * 16 + (lane & 15);
        int k0 = kt * 32 + (lane >> 4) * 8;
        const float* W = (colg < 64) ? Wz : Wr;
        int c = colg & 63;
        short v[8];
        #pragma unroll
        for (int j = 0; j < 8; ++j) {
            int k = k0 + j;
            v[j] = f2bf(W[(k >> 7) * (128 * 64) + (k & 127) * 64 + c]);
        }
        *(bf16x8*)(Bzr + (size_t)ktct * 512 + lane * 8) = *(bf16x8*)v;
    } else if (gid < 4096 + 2048) {                     // h: 32 (kt,ct) x 64 lanes
        int idx = gid - 4096;
        int ktct = idx >> 6, lane = idx & 63;
        int kt = ktct >> 2, ct = ktct & 3;
        int colg = ct * 16 + (lane & 15);
        int k0 = kt * 32 + (lane >> 4) * 8;
        short v[8];
        #pragma unroll
        for (int j = 0; j < 8; ++j) {
            int k = k0 + j;
            v[j] = f2bf(Wh[(k >> 7) * (128 * 64) + (k & 127) * 64 + colg]);
        }
        *(bf16x8*)(Bh + (size_t)ktct * 512 + lane * 8) = *(bf16x8*)v;
    }
}

// ======================= propagation (pull, CSR) =======================
// Px[n][c] = -dinv[n] * sum_e w_e * xd[col_e][c]     (xd already has dinv[col])
__global__ __launch_bounds__(256) void prop2_gather_kernel(
        const int* __restrict__ cursor, const int2* __restrict__ csr,
        const float* __restrict__ dinv,
        const float* __restrict__ xd, const float* __restrict__ hd,
        float* __restrict__ Px, float* __restrict__ Ph) {
    int n = (blockIdx.x * 256 + threadIdx.x) >> 6;
    int lane = threadIdx.x & 63;
    if (n >= N_NODES) return;
    int start = (n == 0) ? 0 : cursor[n - 1];
    int end = cursor[n];
    float ax = 0.f, ah = 0.f;
    int e = start;
    for (; e + 4 <= end; e += 4) {
        int2 c0 = csr[e], c1 = csr[e + 1], c2 = csr[e + 2], c3 = csr[e + 3];
        float x0 = xd[c0.x * C + lane], h0 = hd[c0.x * C + lane];
        float x1 = xd[c1.x * C + lane], h1 = hd[c1.x * C + lane];
        float x2 = xd[c2.x * C + lane], h2 = hd[c2.x * C + lane];
        float x3 = xd[c3.x * C + lane], h3 = hd[c3.x * C + lane];
        ax = fmaf(__int_as_float(c0.y), x0, ax);  ah = fmaf(__int_as_float(c0.y), h0, ah);
        ax = fmaf(__int_as_float(c1.y), x1, ax);  ah = fmaf(__int_as_float(c1.y), h1, ah);
        ax = fmaf(__int_as_float(c2.y), x2, ax);  ah = fmaf(__int_as_float(c2.y), h2, ah);
        ax = fmaf(__int_as_float(c3.y), x3, ax);  ah = fmaf(__int_as_float(c3.y), h3, ah);
    }
    for (; e < end; ++e) {
        int2 cw = csr[e];
        float wv = __int_as_float(cw.y);
        ax = fmaf(wv, xd[cw.x * C + lane], ax);
        ah = fmaf(wv, hd[cw.x * C + lane], ah);
    }
    float s = -dinv[n];
    Px[n * C + lane] = s * ax;
    Ph[n * C + lane] = s * ah;
}

__global__ __launch_bounds__(256) void prop1_gather_kernel(
        const int* __restrict__ cursor, const int2* __restrict__ csr,
        const float* __restrict__ dinv,
        const float* __restrict__ rhd, float* __restrict__ Prh) {
    int n = (blockIdx.x * 256 + threadIdx.x) >> 6;
    int lane = threadIdx.x & 63;
    if (n >= N_NODES) return;
    int start = (n == 0) ? 0 : cursor[n - 1];
    int end = cursor[n];
    float acc = 0.f;
    int e = start;
    for (; e + 4 <= end; e += 4) {
        int2 c0 = csr[e], c1 = csr[e + 1], c2 = csr[e + 2], c3 = csr[e + 3];
        float v0 = rhd[c0.x * C + lane], v1 = rhd[c1.x * C + lane];
        float v2 = rhd[c2.x * C + lane], v3 = rhd[c3.x * C + lane];
        acc = fmaf(__int_as_float(c0.y), v0, acc);
        acc = fmaf(__int_as_float(c1.y), v1, acc);
        acc = fmaf(__int_as_float(c2.y), v2, acc);
        acc = fmaf(__int_as_float(c3.y), v3, acc);
    }
    for (; e < end; ++e) {
        int2 cw = csr[e];
        acc = fmaf(__int_as_float(cw.y), rhd[cw.x * C + lane], acc);
    }
    Prh[n * C + lane] = -dinv[n] * acc;
}

// ======================= dense GEMMs (MFMA bf16) =======================
// One wave = 16 nodes x 128 cols (zr). A = [x|h|Px|Ph] (k: 0-63,64-127,128-191,192-255).
// A-frag: A[m = lane&15][k = kt*32 + (lane>>4)*8 + j].  C/D: col=lane&15, row=(lane>>4)*4+reg.
__global__ __launch_bounds__(256) void gemm_zr_mfma_kernel(
        const float* __restrict__ x,  const float* __restrict__ h,
        const float* __restrict__ Px, const float* __restrict__ Ph,
        const short* __restrict__ Bzr,
        const float* __restrict__ bz, const float* __restrict__ br,
        const float* __restrict__ dinv,
        float* __restrict__ z, float* __restrict__ rh, float* __restrict__ rhd) {
    int wave = (blockIdx.x * 256 + threadIdx.x) >> 6;
    int lane = threadIdx.x & 63;
    int node0 = wave * 16;
    if (node0 >= N_NODES) return;
    int rowA = lane & 15, q = lane >> 4;
    int nodeA = node0 + rowA;

    f32x4 acc[8];
    #pragma unroll
    for (int i = 0; i < 8; ++i) acc[i] = (f32x4){0.f, 0.f, 0.f, 0.f};

    const bf16x8* Bp = (const bf16x8*)Bzr;
    #pragma unroll
    for (int kt = 0; kt < 8; ++kt) {
        const float* src = (kt < 2) ? x : (kt < 4) ? h : (kt < 6) ? Px : Ph;
        const float* p = src + (size_t)nodeA * C + (kt & 1) * 32 + q * 8;
        float4 f0 = *(const float4*)p;
        float4 f1 = *(const float4*)(p + 4);
        short av[8] = {f2bf(f0.x), f2bf(f0.y), f2bf(f0.z), f2bf(f0.w),
                       f2bf(f1.x), f2bf(f1.y), f2bf(f1.z), f2bf(f1.w)};
        bf16x8 a = *(bf16x8*)av;
        #pragma unroll
        for (int ct = 0; ct < 8; ++ct) {
            bf16x8 b = Bp[(kt * 8 + ct) * 64 + lane];
            acc[ct] = __builtin_amdgcn_mfma_f32_16x16x32_bf16(a, b, acc[ct], 0, 0, 0);
        }
    }

    float dv[4];
    #pragma unroll
    for (int r = 0; r < 4; ++r) dv[r] = dinv[node0 + q * 4 + r];

    #pragma unroll
    for (int ct = 0; ct < 8; ++ct) {
        int colg = ct * 16 + (lane & 15);
        if (ct < 4) {                       // z columns
            float bias = bz[colg];
            #pragma unroll
            for (int r = 0; r < 4; ++r) {
                int node = node0 + q * 4 + r;
                z[(size_t)node * C + colg] = fast_sigmoid(acc[ct][r] + bias);
            }
        } else {                            // r columns -> rh, rhd
            int oc = colg - 64;
            float bias = br[oc];
            #pragma unroll
            for (int r = 0; r < 4; ++r) {
                int node = node0 + q * 4 + r;
                float sg = fast_sigmoid(acc[ct][r] + bias);
                float rhv = sg * h[(size_t)node * C + oc];
                rh [(size_t)node * C + oc] = rhv;
                rhd[(size_t)node * C + oc] = rhv * dv[r];
            }
        }
    }
}

// One wave = 16 nodes x 64 cols. A = [x|rh|Px|Prh]. out = (1-z)*h + z*tanh(pre)
__global__ __launch_bounds__(256) void gemm_h_mfma_kernel(
        const float* __restrict__ x,  const float* __restrict__ rh,
        const float* __restrict__ Px, const float* __restrict__ Prh,
        const short* __restrict__ Bh, const float* __restrict__ bh,
        const float* __restrict__ z,  const float* __restrict__ h,
        float* __restrict__ out) {
    int wave = (blockIdx.x * 256 + threadIdx.x) >> 6;
    int lane = threadIdx.x & 63;
    int node0 = wave * 16;
    if (node0 >= N_NODES) return;
    int rowA = lane & 15, q = lane >> 4;
    int nodeA = node0 + rowA;

    f32x4 acc[4];
    #pragma unroll
    for (int i = 0; i < 4; ++i) acc[i] = (f32x4){0.f, 0.f, 0.f, 0.f};

    const bf16x8* Bp = (const bf16x8*)Bh;
    #pragma unroll
    for (int kt = 0; kt < 8; ++kt) {
        const float* src = (kt < 2) ? x : (kt < 4) ? rh : (kt < 6) ? Px : Prh;
        const float* p = src + (size_t)nodeA * C + (kt & 1) * 32 + q * 8;
        float4 f0 = *(const float4*)p;
        float4 f1 = *(const float4*)(p + 4);
        short av[8] = {f2bf(f0.x), f2bf(f0.y), f2bf(f0.z), f2bf(f0.w),
                       f2bf(f1.x), f2bf(f1.y), f2bf(f1.z), f2bf(f1.w)};
        bf16x8 a = *(bf16x8*)av;
        #pragma unroll
        for (int ct = 0; ct < 4; ++ct) {
            bf16x8 b = Bp[(kt * 4 + ct) * 64 + lane];
            acc[ct] = __builtin_amdgcn_mfma_f32_16x16x32_bf16(a, b, acc[ct], 0, 0, 0);
        }
    }

    #pragma unroll
    for (int ct = 0; ct < 4; ++ct) {
        int oc = ct * 16 + (lane & 15);
        float bias = bh[oc];
        #pragma unroll
        for (int r = 0; r < 4; ++r) {
            int node = node0 + q * 4 + r;
            float ht = fast_tanh(acc[ct][r] + bias);
            float zz = z[(size_t)node * C + oc];
            float hv = h[(size_t)node * C + oc];
            out[(size_t)node * C + oc] = (1.f - zz) * hv + zz * ht;
        }
    }
}

extern "C" void kernel_launch(void* const* d_in, const int* in_sizes, int n_in,
                              void* d_out, int out_size, void* d_ws, size_t ws_size,
                              hipStream_t stream) {
    const float* x    = (const float*)d_in[0];
    const int*   eidx = (const int*)  d_in[1];
    const float* w    = (const float*)d_in[2];
    const float* h    = (const float*)d_in[3];
    const float* Wz   = (const float*)d_in[4];
    const float* bz   = (const float*)d_in[5];
    const float* Wr   = (const float*)d_in[6];
    const float* br   = (const float*)d_in[7];
    const float* Wh   = (const float*)d_in[8];
    const float* bh   = (const float*)d_in[9];
    float* out = (float*)d_out;
    float* ws  = (float*)d_ws;

    const int* row = eidx;
    const int* col = eidx + N_EDGES;

    int*   cnt  = (int*)(ws + OFF_CNT);      // becomes cursor / rowptr+1
    int*   part = (int*)(ws + OFF_PART);
    int*   poff = (int*)(ws + OFF_POFF);
    float* dinv = ws + OFF_DINV;
    int2*  csr  = (int2*)(ws + OFF_CSR);
    short* Bzr  = (short*)(ws + OFF_BZR);
    short* Bh   = (short*)(ws + OFF_BH);
    float* Px   = ws + OFF_PX;
    float* Ph   = ws + OFF_PH;               // later Prh
    float* xd   = ws + OFF_XD;               // later rhd
    float* hd   = ws + OFF_HD;               // later rh
    float* rhd  = xd;
    float* rh   = hd;
    float* z    = out;                       // z lives in d_out until gemm_h overwrites

    // ---- CSR build ----
    zero_cnt_kernel<<<(N_PAD / 4 + 255) / 256, 256, 0, stream>>>(cnt);
    hist_kernel<<<(N_EDGES + 255) / 256, 256, 0, stream>>>(row, cnt);
    scan_part_kernel<<<SCAN_BLOCKS, 256, 0, stream>>>(cnt, part);
    scan_root_kernel<<<1, 256, 0, stream>>>(part, poff);
    scan_add_kernel<<<SCAN_BLOCKS, 256, 0, stream>>>(cnt, poff, cnt);
    scatter_kernel<<<(N_EDGES + 255) / 256, 256, 0, stream>>>(row, col, w, cnt, csr);
    degdinv_kernel<<<(N_NODES + 255) / 256, 256, 0, stream>>>(cnt, csr, dinv);

    // ---- feature prescale + weight packing ----
    xdhd_kernel<<<(N_NODES * 16 + 255) / 256, 256, 0, stream>>>(x, h, dinv, xd, hd);
    pack_kernel<<<24, 256, 0, stream>>>(Wz, Wr, Wh, Bzr, Bh);

    // ---- Px = Lhat@x, Ph = Lhat@h ----
    prop2_gather_kernel<<<(N_NODES * 64 + 255) / 256, 256, 0, stream>>>(
        cnt, csr, dinv, xd, hd, Px, Ph);

    // ---- z, rh, rhd ----
    {
        int waves = (N_NODES + 15) / 16;          // 3125
        int blocks = (waves + 3) / 4;             // 782
        gemm_zr_mfma_kernel<<<blocks, 256, 0, stream>>>(
            x, h, Px, Ph, Bzr, bz, br, dinv, z, rh, rhd);
    }

    // ---- Prh = Lhat@(r*h) (into Ph slot) ----
    prop1_gather_kernel<<<(N_NODES * 64 + 255) / 256, 256, 0, stream>>>(
        cnt, csr, dinv, rhd, Ph);

    // ---- candidate + GRU blend ----
    {
        int waves = (N_NODES + 15) / 16;
        int blocks = (waves + 3) / 4;
        gemm_h_mfma_kernel<<<blocks, 256, 0, stream>>>(
            x, rh, Px, Ph, Bh, bh, z, h, out);
    }
}

// Round 5
// 307.631 us; speedup vs baseline: 3.0572x; 1.0569x over previous
//
#include <hip/hip_runtime.h>
#include <cstdint>

#define N_NODES 50000
#define N_EDGES 800000
#define C 64
#define N_PAD 50176                 // 196 * 256
#define SCAN_BLOCKS 196

typedef __attribute__((ext_vector_type(8))) short bf16x8;   // 8 bf16 in 4 VGPRs
typedef __attribute__((ext_vector_type(4))) float f32x4;

// ---------------- workspace layout (float units) ----------------
// xh: packed (bf16 hd | bf16 xd) per channel -> one uint gather serves both props.
// rhd: bf16 ushort. Px/Ph fp32 (MFMA A-operands).
static constexpr size_t OFF_CNT  = 0;                        // N_PAD ints (count -> cursor)
static constexpr size_t OFF_PART = 50176;                    // 256 ints
static constexpr size_t OFF_POFF = 50432;                    // 256 ints
static constexpr size_t OFF_DINV = 50688;                    // N floats
static constexpr size_t OFF_CSR  = 100864;                   // E int2
static constexpr size_t OFF_BZR  = OFF_CSR + 2 * (size_t)N_EDGES;   // 32768 sh = 16384 fl
static constexpr size_t OFF_BH   = OFF_BZR + 16384;                 // 16384 sh = 8192 fl
static constexpr size_t OFF_PX   = OFF_BH + 8192;                   // N*C fl
static constexpr size_t OFF_PH   = OFF_PX + (size_t)N_NODES * C;    // N*C fl (later Prh)
static constexpr size_t OFF_XH   = OFF_PH + (size_t)N_NODES * C;    // N*C uints
static constexpr size_t OFF_RH   = OFF_XH + (size_t)N_NODES * C;    // N*C fl
static constexpr size_t OFF_RHD  = OFF_RH + (size_t)N_NODES * C;    // N*C ushort = N*C/2 fl
// total = OFF_RHD + N*C/2 = 16,125,440 fl = 64.5 MB (round-0 proved >= 67.4 MB OK)

__device__ __forceinline__ short f2bf(float f) {             // RNE fp32 -> bf16
    unsigned u = __float_as_uint(f);
    u += 0x7fffu + ((u >> 16) & 1u);
    return (short)(u >> 16);
}
__device__ __forceinline__ float bf_lo(unsigned v) {         // low bf16 -> f32
    return __uint_as_float(v << 16);
}
__device__ __forceinline__ float bf_hi(unsigned v) {         // high bf16 -> f32
    return __uint_as_float(v & 0xffff0000u);
}
__device__ __forceinline__ float fast_sigmoid(float v) {
    return 1.f / (1.f + __expf(-v));
}
__device__ __forceinline__ float fast_tanh(float v) {
    return 1.f - 2.f / (__expf(2.f * v) + 1.f);
}

// ======================= CSR build =======================
__global__ void zero_cnt_kernel(int* __restrict__ p) {
    int i = blockIdx.x * blockDim.x + threadIdx.x;
    if (i < N_PAD / 4) ((int4*)p)[i] = make_int4(0, 0, 0, 0);
}

__global__ void hist_kernel(const int* __restrict__ row, int* __restrict__ cnt) {
    int e = blockIdx.x * blockDim.x + threadIdx.x;
    if (e < N_EDGES) atomicAdd(&cnt[row[e]], 1);
}

__global__ __launch_bounds__(256) void scan_part_kernel(const int* __restrict__ cnt,
                                                        int* __restrict__ part) {
    __shared__ int s[256];
    int t = threadIdx.x;
    s[t] = cnt[blockIdx.x * 256 + t];
    __syncthreads();
    for (int d = 128; d > 0; d >>= 1) {
        if (t < d) s[t] += s[t + d];
        __syncthreads();
    }
    if (t == 0) part[blockIdx.x] = s[0];
}

__global__ __launch_bounds__(256) void scan_root_kernel(const int* __restrict__ part,
                                                        int* __restrict__ poff) {
    __shared__ int s[256];
    int t = threadIdx.x;
    int v = (t < SCAN_BLOCKS) ? part[t] : 0;
    s[t] = v;
    __syncthreads();
    for (int d = 1; d < 256; d <<= 1) {
        int add = (t >= d) ? s[t - d] : 0;
        __syncthreads();
        s[t] += add;
        __syncthreads();
    }
    if (t < SCAN_BLOCKS) poff[t] = s[t] - v;
}

__global__ __launch_bounds__(256) void scan_add_kernel(const int* __restrict__ cnt,
                                                       const int* __restrict__ poff,
                                                       int* __restrict__ cursor) {
    __shared__ int s[256];
    int t = threadIdx.x;
    int i = blockIdx.x * 256 + t;
    int v = cnt[i];
    s[t] = v;
    __syncthreads();
    for (int d = 1; d < 256; d <<= 1) {
        int add = (t >= d) ? s[t - d] : 0;
        __syncthreads();
        s[t] += add;
        __syncthreads();
    }
    cursor[i] = s[t] - v + poff[blockIdx.x];
}

// after this, cursor[n] == rowptr[n+1]
__global__ void scatter_kernel(const int* __restrict__ row, const int* __restrict__ col,
                               const float* __restrict__ w,
                               int* __restrict__ cursor, int2* __restrict__ csr) {
    int e = blockIdx.x * blockDim.x + threadIdx.x;
    if (e >= N_EDGES) return;
    int pos = atomicAdd(&cursor[row[e]], 1);
    csr[pos] = make_int2(col[e], __float_as_int(w[e]));
}

__global__ void degdinv_kernel(const int* __restrict__ cursor, const int2* __restrict__ csr,
                               float* __restrict__ dinv) {
    int n = blockIdx.x * blockDim.x + threadIdx.x;
    if (n >= N_NODES) return;
    int start = (n == 0) ? 0 : cursor[n - 1];
    int end = cursor[n];
    float d = 0.f;
    for (int e = start; e < end; ++e) d += __int_as_float(csr[e].y);
    dinv[n] = (d > 0.f) ? rsqrtf(d) : 0.f;
}

// xh[n*64+c] = (bf16(h*d) << 16) | bf16(x*d)   (uint4-vectorized)
__global__ void xh_pack_kernel(const float* __restrict__ x, const float* __restrict__ h,
                               const float* __restrict__ dinv, unsigned* __restrict__ xh) {
    int i = blockIdx.x * blockDim.x + threadIdx.x;   // N*16 groups of 4 channels
    if (i >= N_NODES * 16) return;
    float d = dinv[i >> 4];
    float4 xv = ((const float4*)x)[i];
    float4 hv = ((const float4*)h)[i];
    uint4 o;
    o.x = ((unsigned)(unsigned short)f2bf(hv.x * d) << 16) | (unsigned short)f2bf(xv.x * d);
    o.y = ((unsigned)(unsigned short)f2bf(hv.y * d) << 16) | (unsigned short)f2bf(xv.y * d);
    o.z = ((unsigned)(unsigned short)f2bf(hv.z * d) << 16) | (unsigned short)f2bf(xv.z * d);
    o.w = ((unsigned)(unsigned short)f2bf(hv.w * d) << 16) | (unsigned short)f2bf(xv.w * d);
    ((uint4*)xh)[i] = o;
}

// Pack weights into bf16 B-fragment order for mfma_f32_16x16x32_bf16.
// Bpack[(kt*NCT+ct)*512 + lane*8 + j] = B[kt*32 + (lane>>4)*8 + j][ct*16 + (lane&15)]
__global__ void pack_kernel(const float* __restrict__ Wz, const float* __restrict__ Wr,
                            const float* __restrict__ Wh,
                            short* __restrict__ Bzr, short* __restrict__ Bh) {
    int gid = blockIdx.x * blockDim.x + threadIdx.x;   // 6144 threads
    if (gid < 4096) {                                   // zr: 64 (kt,ct) x 64 lanes
        int ktct = gid >> 6, lane = gid & 63;
        int kt = ktct >> 3, ct = ktct & 7;
        int colg = ct * 16 + (lane & 15);
        int k0 = kt * 32 + (lane >> 4) * 8;
        const float* W = (colg < 64) ? Wz : Wr;
        int c = colg & 63;
        short v[8];
        #pragma unroll
        for (int j = 0; j < 8; ++j) {
            int k = k0 + j;
            v[j] = f2bf(W[(k >> 7) * (128 * 64) + (k & 127) * 64 + c]);
        }
        *(bf16x8*)(Bzr + (size_t)ktct * 512 + lane * 8) = *(bf16x8*)v;
    } else if (gid < 4096 + 2048) {                     // h: 32 (kt,ct) x 64 lanes
        int idx = gid - 4096;
        int ktct = idx >> 6, lane = idx & 63;
        int kt = ktct >> 2, ct = ktct & 3;
        int colg = ct * 16 + (lane & 15);
        int k0 = kt * 32 + (lane >> 4) * 8;
        short v[8];
        #pragma unroll
        for (int j = 0; j < 8; ++j) {
            int k = k0 + j;
            v[j] = f2bf(Wh[(k >> 7) * (128 * 64) + (k & 127) * 64 + colg]);
        }
        *(bf16x8*)(Bh + (size_t)ktct * 512 + lane * 8) = *(bf16x8*)v;
    }
}

// ======================= propagation (pull, CSR) =======================
// Px[n][c] = -dinv[n] * sum_e w_e * xd[col_e][c]   (xd/hd packed bf16 in xh)
__global__ __launch_bounds__(256) void prop2_gather_kernel(
        const int* __restrict__ cursor, const int2* __restrict__ csr,
        const float* __restrict__ dinv, const unsigned* __restrict__ xh,
        float* __restrict__ Px, float* __restrict__ Ph) {
    int n = (blockIdx.x * 256 + threadIdx.x) >> 6;
    int lane = threadIdx.x & 63;
    if (n >= N_NODES) return;
    int start = (n == 0) ? 0 : cursor[n - 1];
    int end = cursor[n];
    float ax = 0.f, ah = 0.f;
    int e = start;
    for (; e + 4 <= end; e += 4) {
        int2 c0 = csr[e], c1 = csr[e + 1], c2 = csr[e + 2], c3 = csr[e + 3];
        unsigned v0 = xh[c0.x * C + lane];
        unsigned v1 = xh[c1.x * C + lane];
        unsigned v2 = xh[c2.x * C + lane];
        unsigned v3 = xh[c3.x * C + lane];
        float w0 = __int_as_float(c0.y), w1 = __int_as_float(c1.y);
        float w2 = __int_as_float(c2.y), w3 = __int_as_float(c3.y);
        ax = fmaf(w0, bf_lo(v0), ax);  ah = fmaf(w0, bf_hi(v0), ah);
        ax = fmaf(w1, bf_lo(v1), ax);  ah = fmaf(w1, bf_hi(v1), ah);
        ax = fmaf(w2, bf_lo(v2), ax);  ah = fmaf(w2, bf_hi(v2), ah);
        ax = fmaf(w3, bf_lo(v3), ax);  ah = fmaf(w3, bf_hi(v3), ah);
    }
    for (; e < end; ++e) {
        int2 cw = csr[e];
        unsigned v = xh[cw.x * C + lane];
        float wv = __int_as_float(cw.y);
        ax = fmaf(wv, bf_lo(v), ax);
        ah = fmaf(wv, bf_hi(v), ah);
    }
    float s = -dinv[n];
    Px[n * C + lane] = s * ax;
    Ph[n * C + lane] = s * ah;
}

__global__ __launch_bounds__(256) void prop1_gather_kernel(
        const int* __restrict__ cursor, const int2* __restrict__ csr,
        const float* __restrict__ dinv,
        const unsigned short* __restrict__ rhd, float* __restrict__ Prh) {
    int n = (blockIdx.x * 256 + threadIdx.x) >> 6;
    int lane = threadIdx.x & 63;
    if (n >= N_NODES) return;
    int start = (n == 0) ? 0 : cursor[n - 1];
    int end = cursor[n];
    float acc = 0.f;
    int e = start;
    for (; e + 4 <= end; e += 4) {
        int2 c0 = csr[e], c1 = csr[e + 1], c2 = csr[e + 2], c3 = csr[e + 3];
        float v0 = __uint_as_float((unsigned)rhd[c0.x * C + lane] << 16);
        float v1 = __uint_as_float((unsigned)rhd[c1.x * C + lane] << 16);
        float v2 = __uint_as_float((unsigned)rhd[c2.x * C + lane] << 16);
        float v3 = __uint_as_float((unsigned)rhd[c3.x * C + lane] << 16);
        acc = fmaf(__int_as_float(c0.y), v0, acc);
        acc = fmaf(__int_as_float(c1.y), v1, acc);
        acc = fmaf(__int_as_float(c2.y), v2, acc);
        acc = fmaf(__int_as_float(c3.y), v3, acc);
    }
    for (; e < end; ++e) {
        int2 cw = csr[e];
        float v = __uint_as_float((unsigned)rhd[cw.x * C + lane] << 16);
        acc = fmaf(__int_as_float(cw.y), v, acc);
    }
    Prh[n * C + lane] = -dinv[n] * acc;
}

// ======================= dense GEMMs (MFMA bf16) =======================
// One wave = 16 nodes x 128 cols (zr). A = [x|h|Px|Ph].
// A-frag: A[m = lane&15][k = kt*32 + (lane>>4)*8 + j].  C/D: col=lane&15, row=(lane>>4)*4+reg.
__global__ __launch_bounds__(256) void gemm_zr_mfma_kernel(
        const float* __restrict__ x,  const float* __restrict__ h,
        const float* __restrict__ Px, const float* __restrict__ Ph,
        const short* __restrict__ Bzr,
        const float* __restrict__ bz, const float* __restrict__ br,
        const float* __restrict__ dinv,
        float* __restrict__ z, float* __restrict__ rh, unsigned short* __restrict__ rhd) {
    int wave = (blockIdx.x * 256 + threadIdx.x) >> 6;
    int lane = threadIdx.x & 63;
    int node0 = wave * 16;
    if (node0 >= N_NODES) return;
    int rowA = lane & 15, q = lane >> 4;
    int nodeA = node0 + rowA;

    f32x4 acc[8];
    #pragma unroll
    for (int i = 0; i < 8; ++i) acc[i] = (f32x4){0.f, 0.f, 0.f, 0.f};

    const bf16x8* Bp = (const bf16x8*)Bzr;
    #pragma unroll
    for (int kt = 0; kt < 8; ++kt) {
        const float* src = (kt < 2) ? x : (kt < 4) ? h : (kt < 6) ? Px : Ph;
        const float* p = src + (size_t)nodeA * C + (kt & 1) * 32 + q * 8;
        float4 f0 = *(const float4*)p;
        float4 f1 = *(const float4*)(p + 4);
        short av[8] = {f2bf(f0.x), f2bf(f0.y), f2bf(f0.z), f2bf(f0.w),
                       f2bf(f1.x), f2bf(f1.y), f2bf(f1.z), f2bf(f1.w)};
        bf16x8 a = *(bf16x8*)av;
        #pragma unroll
        for (int ct = 0; ct < 8; ++ct) {
            bf16x8 b = Bp[(kt * 8 + ct) * 64 + lane];
            acc[ct] = __builtin_amdgcn_mfma_f32_16x16x32_bf16(a, b, acc[ct], 0, 0, 0);
        }
    }

    float dv[4];
    #pragma unroll
    for (int r = 0; r < 4; ++r) dv[r] = dinv[node0 + q * 4 + r];

    #pragma unroll
    for (int ct = 0; ct < 8; ++ct) {
        int colg = ct * 16 + (lane & 15);
        if (ct < 4) {                       // z columns
            float bias = bz[colg];
            #pragma unroll
            for (int r = 0; r < 4; ++r) {
                int node = node0 + q * 4 + r;
                z[(size_t)node * C + colg] = fast_sigmoid(acc[ct][r] + bias);
            }
        } else {                            // r columns -> rh (fp32), rhd (bf16)
            int oc = colg - 64;
            float bias = br[oc];
            #pragma unroll
            for (int r = 0; r < 4; ++r) {
                int node = node0 + q * 4 + r;
                float sg = fast_sigmoid(acc[ct][r] + bias);
                float rhv = sg * h[(size_t)node * C + oc];
                rh [(size_t)node * C + oc] = rhv;
                rhd[(size_t)node * C + oc] = (unsigned short)f2bf(rhv * dv[r]);
            }
        }
    }
}

// One wave = 16 nodes x 64 cols. A = [x|rh|Px|Prh]. out = (1-z)*h + z*tanh(pre)
__global__ __launch_bounds__(256) void gemm_h_mfma_kernel(
        const float* __restrict__ x,  const float* __restrict__ rh,
        const float* __restrict__ Px, const float* __restrict__ Prh,
        const short* __restrict__ Bh, const float* __restrict__ bh,
        const float* __restrict__ z,  const float* __restrict__ h,
        float* __restrict__ out) {
    int wave = (blockIdx.x * 256 + threadIdx.x) >> 6;
    int lane = threadIdx.x & 63;
    int node0 = wave * 16;
    if (node0 >= N_NODES) return;
    int rowA = lane & 15, q = lane >> 4;
    int nodeA = node0 + rowA;

    f32x4 acc[4];
    #pragma unroll
    for (int i = 0; i < 4; ++i) acc[i] = (f32x4){0.f, 0.f, 0.f, 0.f};

    const bf16x8* Bp = (const bf16x8*)Bh;
    #pragma unroll
    for (int kt = 0; kt < 8; ++kt) {
        const float* src = (kt < 2) ? x : (kt < 4) ? rh : (kt < 6) ? Px : Prh;
        const float* p = src + (size_t)nodeA * C + (kt & 1) * 32 + q * 8;
        float4 f0 = *(const float4*)p;
        float4 f1 = *(const float4*)(p + 4);
        short av[8] = {f2bf(f0.x), f2bf(f0.y), f2bf(f0.z), f2bf(f0.w),
                       f2bf(f1.x), f2bf(f1.y), f2bf(f1.z), f2bf(f1.w)};
        bf16x8 a = *(bf16x8*)av;
        #pragma unroll
        for (int ct = 0; ct < 4; ++ct) {
            bf16x8 b = Bp[(kt * 4 + ct) * 64 + lane];
            acc[ct] = __builtin_amdgcn_mfma_f32_16x16x32_bf16(a, b, acc[ct], 0, 0, 0);
        }
    }

    #pragma unroll
    for (int ct = 0; ct < 4; ++ct) {
        int oc = ct * 16 + (lane & 15);
        float bias = bh[oc];
        #pragma unroll
        for (int r = 0; r < 4; ++r) {
            int node = node0 + q * 4 + r;
            float ht = fast_tanh(acc[ct][r] + bias);
            float zz = z[(size_t)node * C + oc];
            float hv = h[(size_t)node * C + oc];
            out[(size_t)node * C + oc] = (1.f - zz) * hv + zz * ht;
        }
    }
}

extern "C" void kernel_launch(void* const* d_in, const int* in_sizes, int n_in,
                              void* d_out, int out_size, void* d_ws, size_t ws_size,
                              hipStream_t stream) {
    const float* x    = (const float*)d_in[0];
    const int*   eidx = (const int*)  d_in[1];
    const float* w    = (const float*)d_in[2];
    const float* h    = (const float*)d_in[3];
    const float* Wz   = (const float*)d_in[4];
    const float* bz   = (const float*)d_in[5];
    const float* Wr   = (const float*)d_in[6];
    const float* br   = (const float*)d_in[7];
    const float* Wh   = (const float*)d_in[8];
    const float* bh   = (const float*)d_in[9];
    float* out = (float*)d_out;
    float* ws  = (float*)d_ws;

    const int* row = eidx;
    const int* col = eidx + N_EDGES;

    int*            cnt  = (int*)(ws + OFF_CNT);      // becomes cursor / rowptr+1
    int*            part = (int*)(ws + OFF_PART);
    int*            poff = (int*)(ws + OFF_POFF);
    float*          dinv = ws + OFF_DINV;
    int2*           csr  = (int2*)(ws + OFF_CSR);
    short*          Bzr  = (short*)(ws + OFF_BZR);
    short*          Bh   = (short*)(ws + OFF_BH);
    float*          Px   = ws + OFF_PX;
    float*          Ph   = ws + OFF_PH;               // later Prh
    unsigned*       xh   = (unsigned*)(ws + OFF_XH);
    float*          rh   = ws + OFF_RH;
    unsigned short* rhd  = (unsigned short*)(ws + OFF_RHD);
    float*          z    = out;                       // z lives in d_out until gemm_h

    // ---- CSR build ----
    zero_cnt_kernel<<<(N_PAD / 4 + 255) / 256, 256, 0, stream>>>(cnt);
    hist_kernel<<<(N_EDGES + 255) / 256, 256, 0, stream>>>(row, cnt);
    scan_part_kernel<<<SCAN_BLOCKS, 256, 0, stream>>>(cnt, part);
    scan_root_kernel<<<1, 256, 0, stream>>>(part, poff);
    scan_add_kernel<<<SCAN_BLOCKS, 256, 0, stream>>>(cnt, poff, cnt);
    scatter_kernel<<<(N_EDGES + 255) / 256, 256, 0, stream>>>(row, col, w, cnt, csr);
    degdinv_kernel<<<(N_NODES + 255) / 256, 256, 0, stream>>>(cnt, csr, dinv);

    // ---- feature prescale+pack (bf16) + weight packing ----
    xh_pack_kernel<<<(N_NODES * 16 + 255) / 256, 256, 0, stream>>>(x, h, dinv, xh);
    pack_kernel<<<24, 256, 0, stream>>>(Wz, Wr, Wh, Bzr, Bh);

    // ---- Px = Lhat@x, Ph = Lhat@h ----
    prop2_gather_kernel<<<(N_NODES * 64 + 255) / 256, 256, 0, stream>>>(
        cnt, csr, dinv, xh, Px, Ph);

    // ---- z, rh, rhd ----
    {
        int waves = (N_NODES + 15) / 16;          // 3125
        int blocks = (waves + 3) / 4;             // 782
        gemm_zr_mfma_kernel<<<blocks, 256, 0, stream>>>(
            x, h, Px, Ph, Bzr, bz, br, dinv, z, rh, rhd);
    }

    // ---- Prh = Lhat@(r*h) (into Ph slot) ----
    prop1_gather_kernel<<<(N_NODES * 64 + 255) / 256, 256, 0, stream>>>(
        cnt, csr, dinv, rhd, Ph);

    // ---- candidate + GRU blend ----
    {
        int waves = (N_NODES + 15) / 16;
        int blocks = (waves + 3) / 4;
        gemm_h_mfma_kernel<<<blocks, 256, 0, stream>>>(
            x, rh, Px, Ph, Bh, bh, z, h, out);
    }
}